// Round 2
// baseline (22198.218 us; speedup 1.0000x reference)
//
#include <hip/hip_runtime.h>

// ---------------------------------------------------------------------------
// Decoder_49005576847865 — incremental KV-free decoder (enc-identity cross-attn)
//   B=16, d=512, H=8 (dh=64), L=4, dff=2048, Lenc=2048, 16 steps, vocab=256.
// Round 2: workspace-lean (~41 MB; fp32-enc fallback ~9 MB).
//   Cross-attn uses softmax shift-invariance: logits = (qc Wk^T) . enc_key,
//   weighted enc sum z, then z @ Wv + bv. No K/V cache needed.
// ---------------------------------------------------------------------------

typedef unsigned short ushort_t;
typedef __attribute__((ext_vector_type(4))) float f32x4;
typedef __attribute__((ext_vector_type(8))) unsigned short us8;
typedef __attribute__((ext_vector_type(4))) unsigned short us4;

__device__ __forceinline__ float bf2f(ushort_t u) {
    union { unsigned int i; float f; } v; v.i = ((unsigned int)u) << 16; return v.f;
}
__device__ __forceinline__ ushort_t f2bf(float f) {
    union { unsigned int i; float f; } v; v.f = f;
    return (ushort_t)((v.i + 0x7FFF + ((v.i >> 16) & 1)) >> 16);   // RNE
}
__device__ __forceinline__ float wave_sum(float v) {
    #pragma unroll
    for (int m = 32; m; m >>= 1) v += __shfl_xor(v, m);
    return v;
}

// Stage one 512-wide row into LDS (wave-local), optionally LayerNorm'd.
// Caller must __syncthreads() before cross-wave reads (we only read same-wave,
// but we sync anyway for safety).
__device__ __forceinline__ void stage_ln_wave(const float* __restrict__ row,
                                              const float* __restrict__ g,
                                              const float* __restrict__ be,
                                              int use_ln, float* xs, int lane) {
    float loc[8];
    float s = 0.f;
    #pragma unroll
    for (int i = 0; i < 8; i++) { loc[i] = row[lane + i * 64]; s += loc[i]; }
    if (use_ln) {
        s = wave_sum(s);
        float mu = s * (1.f / 512.f);
        float var = 0.f;
        #pragma unroll
        for (int i = 0; i < 8; i++) { float d = loc[i] - mu; var += d * d; }
        var = wave_sum(var);
        float rstd = rsqrtf(var * (1.f / 512.f) + 1e-6f);
        #pragma unroll
        for (int i = 0; i < 8; i++) {
            int c = lane + i * 64;
            xs[c] = (loc[i] - mu) * rstd * g[c] + be[c];
        }
    } else {
        #pragma unroll
        for (int i = 0; i < 8; i++) xs[lane + i * 64] = loc[i];
    }
}

__device__ __forceinline__ float dot512(const float* xs, const float* __restrict__ W,
                                        int col, int N) {
    float acc = 0.f;
    for (int r = 0; r < 512; r += 8) {
        #pragma unroll
        for (int j = 0; j < 8; j++) acc += xs[r + j] * W[(size_t)(r + j) * N + col];
    }
    return acc;
}

// ------------------------------- setup kernels -----------------------------

__global__ void k_posenc(float* __restrict__ pos) {
    int p = blockIdx.x, i = threadIdx.x;
    float expo = (2.0f * (float)(i >> 1)) / 512.0f;
    float f = powf(10000.0f, -expo);
    float ang = (float)p * f;
    pos[p * 512 + i] = ((i & 1) == 0) ? sinf(ang) : cosf(ang);
}

__global__ __launch_bounds__(256) void k_padflag(const float* __restrict__ in,
                                                 float* __restrict__ pad) {
    int lane = threadIdx.x & 63, w = threadIdx.x >> 6;
    int key = blockIdx.x * 4 + w, b = blockIdx.y;
    const float* p = in + ((size_t)b * 2048 + key) * 128;
    int ok = (p[lane] == 0.f) && (p[lane + 64] == 0.f);
    int all = __all(ok);
    if (lane == 0) pad[b * 2048 + key] = all ? 1.f : 0.f;
}

__global__ void k_cvt_enc(const float* __restrict__ in, ushort_t* __restrict__ out) {
    size_t i = ((size_t)blockIdx.x * 256 + threadIdx.x) * 4;
    float4 v = *(const float4*)&in[i];
    us4 o; o[0] = f2bf(v.x); o[1] = f2bf(v.y); o[2] = f2bf(v.z); o[3] = f2bf(v.w);
    *(us4*)&out[i] = o;
}

// ------------------------------ per-step kernels ---------------------------
// All "b4" kernels: 256 threads = 4 waves; wave w handles batch b = bIdx.y*4+w.

__global__ __launch_bounds__(256) void k_embed_b4(
    const float* __restrict__ dout, const float* __restrict__ embW,
    const float* __restrict__ embB, const float* __restrict__ pos,
    float* __restrict__ x0, int t) {
    __shared__ float tok[4][256];
    int lane = threadIdx.x & 63, w = threadIdx.x >> 6;
    int b = blockIdx.y * 4 + w;
    #pragma unroll
    for (int i = 0; i < 4; i++)
        tok[w][lane + i * 64] = (t == 0) ? 1.f
            : dout[((size_t)b * 16 + (t - 1)) * 256 + lane + i * 64];
    __syncthreads();
    int col = blockIdx.x * 64 + lane;
    float acc = 0.f;
    for (int r = 0; r < 256; r += 8) {
        #pragma unroll
        for (int j = 0; j < 8; j++) acc += tok[w][r + j] * embW[(size_t)(r + j) * 512 + col];
    }
    x0[(size_t)b * 512 + col] = (acc + embB[col]) * 22.627416997969522f + pos[t * 512 + col];
}

// q/k/v projections for self-attn. grid (24, 4): m = bx>>3 in {q,k,v}.
__global__ __launch_bounds__(256) void k_qkvcol(
    const float* __restrict__ src, const float* __restrict__ g,
    const float* __restrict__ be, int use_ln,
    const float* __restrict__ W, const float* __restrict__ bias,
    float* __restrict__ qbuf, float* __restrict__ selfK, float* __restrict__ selfV,
    int l, int t) {
    __shared__ float xa[4][512];
    int lane = threadIdx.x & 63, w = threadIdx.x >> 6;
    int b = blockIdx.y * 4 + w;
    int m = blockIdx.x >> 3, colblk = blockIdx.x & 7;
    stage_ln_wave(src + (size_t)b * 512, g, be, use_ln, xa[w], lane);
    __syncthreads();
    int col = colblk * 64 + lane;
    const float* Wm = W + (size_t)m * 262144;
    float acc = dot512(xa[w], Wm, col, 512) + bias[m * 512 + col];
    if (m == 0) qbuf[(size_t)b * 512 + col] = acc;
    else {
        float* dst = (m == 1) ? selfK : selfV;
        dst[(((size_t)l * 16 + b) * 16 + t) * 512 + col] = acc;
    }
}

__global__ __launch_bounds__(256) void k_selfout_b4(
    const float* __restrict__ src, const float* __restrict__ g,
    const float* __restrict__ be, int use_ln,
    const float* __restrict__ qbuf, const float* __restrict__ selfK,
    const float* __restrict__ selfV,
    const float* __restrict__ Wo, const float* __restrict__ bo,
    float* __restrict__ y1, int l, int t) {
    __shared__ float xs[4][512], qs[4][512], as[4][512];
    __shared__ float lg[4][8][16], wsm[4][8][16];
    int lane = threadIdx.x & 63, w = threadIdx.x >> 6;
    int b = blockIdx.y * 4 + w;
    stage_ln_wave(src + (size_t)b * 512, g, be, use_ln, xs[w], lane);
    #pragma unroll
    for (int i = 0; i < 8; i++) qs[w][lane + i * 64] = qbuf[(size_t)b * 512 + lane + i * 64];
    __syncthreads();
    const float* Kb = selfK + (((size_t)l * 16 + b) * 16) * 512;
    const float* Vb = selfV + (((size_t)l * 16 + b) * 16) * 512;
    #pragma unroll
    for (int i = 0; i < 2; i++) {
        int task = lane + i * 64;
        int h = task >> 4, j = task & 15;
        if (j <= t) {
            const float* kr = Kb + (size_t)j * 512 + h * 64;
            const float* qh = &qs[w][h * 64];
            float s = 0.f;
            #pragma unroll
            for (int d = 0; d < 64; d++) s += qh[d] * kr[d];
            lg[w][h][j] = s * 0.125f;
        }
    }
    __syncthreads();
    if (lane < 8) {
        int h = lane;
        float m = -1e30f;
        for (int j = 0; j <= t; j++) m = fmaxf(m, lg[w][h][j]);
        float ssum = 0.f;
        for (int j = 0; j <= t; j++) { float e = __expf(lg[w][h][j] - m); wsm[w][h][j] = e; ssum += e; }
        float inv = 1.f / ssum;
        for (int j = 0; j <= t; j++) wsm[w][h][j] *= inv;
    }
    __syncthreads();
    #pragma unroll
    for (int i = 0; i < 8; i++) {
        int c = lane + i * 64, h = c >> 6;
        float a = 0.f;
        for (int j = 0; j <= t; j++) a += wsm[w][h][j] * Vb[(size_t)j * 512 + c];
        as[w][c] = a;
    }
    __syncthreads();
    int col = blockIdx.x * 64 + lane;
    float acc = dot512(as[w], Wo, col, 512);
    y1[(size_t)b * 512 + col] = acc + bo[col] + xs[w][col];
}

// generic: out[b][col] = LN?(srcA)@W + bias (+LN(srcR)[col]) (relu?)
__global__ __launch_bounds__(256) void k_colgemm_b4(
    const float* __restrict__ srcA, int lnA,
    const float* __restrict__ gA, const float* __restrict__ bA,
    const float* __restrict__ srcR, const float* __restrict__ gR,
    const float* __restrict__ bR, int addR,
    const float* __restrict__ W, const float* __restrict__ bias, int N,
    float* __restrict__ outp, int ostride, int relu) {
    __shared__ float xa[4][512];
    __shared__ float xr[4][512];
    int lane = threadIdx.x & 63, w = threadIdx.x >> 6;
    int b = blockIdx.y * 4 + w;
    stage_ln_wave(srcA + (size_t)b * 512, gA, bA, lnA, xa[w], lane);
    if (addR) stage_ln_wave(srcR + (size_t)b * 512, gR, bR, 1, xr[w], lane);
    __syncthreads();
    int col = blockIdx.x * 64 + lane;
    float acc = dot512(xa[w], W, col, N) + bias[col];
    if (addR) acc += xr[w][col];
    if (relu) acc = fmaxf(acc, 0.f);
    outp[(size_t)b * ostride + col] = acc;
}

// qt[b][h][D] = 0.125 * sum_d qc[b][h*64+d] * Wk[D][h*64+d]. grid (8, 4).
__global__ __launch_bounds__(256) void k_qt_b4(
    const float* __restrict__ qc, const float* __restrict__ Wk,
    float* __restrict__ qt) {
    __shared__ float qh[4][64];
    int lane = threadIdx.x & 63, w = threadIdx.x >> 6;
    int h = blockIdx.x, b = blockIdx.y * 4 + w;
    qh[w][lane] = qc[(size_t)b * 512 + h * 64 + lane];
    __syncthreads();
    #pragma unroll
    for (int it = 0; it < 8; it++) {
        int D = it * 64 + lane;
        const float* wrow = Wk + (size_t)D * 512 + h * 64;
        float acc = 0.f;
        #pragma unroll
        for (int dd = 0; dd < 64; dd += 4) {
            float4 wv = *(const float4*)&wrow[dd];
            acc += qh[w][dd] * wv.x + qh[w][dd + 1] * wv.y
                 + qh[w][dd + 2] * wv.z + qh[w][dd + 3] * wv.w;
        }
        qt[((size_t)b * 8 + h) * 512 + D] = acc * 0.125f;
    }
}

// cross-attn over enc directly. grid (16 chunks of 128 keys, 16 b), 256 thr.
// Online softmax over 16 groups of 8 keys; outputs per-chunk m, s, z[8][512].
template<int BF16>
__global__ __launch_bounds__(256) void k_flash2(
    const void* __restrict__ encp, const float* __restrict__ qt,
    const float* __restrict__ pad,
    float* __restrict__ Pm2, float* __restrict__ Ps2, float* __restrict__ Pz) {
    __shared__ float qts[4096];   // [h][D]
    __shared__ float rows[4096];  // [k8][D]
    __shared__ float lge[8][8];   // [h][k8]: raw logit then exp
    __shared__ float mh[8], sh[8], fh[8];
    int tid = threadIdx.x;
    int c = blockIdx.x, b = blockIdx.y;
    for (int i = tid; i < 4096; i += 256) qts[i] = qt[(size_t)b * 4096 + i];
    if (tid < 8) { mh[tid] = -1e30f; sh[tid] = 0.f; fh[tid] = 1.f; }
    int h = tid >> 5, ii = tid & 31;
    f32x4 z4[4];
    #pragma unroll
    for (int jj = 0; jj < 4; jj++) z4[jj] = (f32x4){0.f, 0.f, 0.f, 0.f};
    __syncthreads();
    for (int g = 0; g < 16; ++g) {
        int key0 = c * 128 + g * 8;
        if (BF16) {
            const ushort_t* enc = (const ushort_t*)encp;
            #pragma unroll
            for (int it = 0; it < 2; ++it) {
                int off = tid * 8 + it * 2048;
                int kr = off >> 9, D = off & 511;
                us8 v = *(const us8*)&enc[((size_t)b * 2048 + key0 + kr) * 512 + D];
                float4 lo = {bf2f(v[0]), bf2f(v[1]), bf2f(v[2]), bf2f(v[3])};
                float4 hi = {bf2f(v[4]), bf2f(v[5]), bf2f(v[6]), bf2f(v[7])};
                *(float4*)&rows[kr * 512 + D] = lo;
                *(float4*)&rows[kr * 512 + D + 4] = hi;
            }
        } else {
            const float* enc = (const float*)encp;
            #pragma unroll
            for (int it = 0; it < 4; ++it) {
                int off = tid * 4 + it * 1024;
                int kr = off >> 9, D = off & 511;
                *(float4*)&rows[kr * 512 + D] =
                    *(const float4*)&enc[((size_t)b * 2048 + key0 + kr) * 512 + D];
            }
        }
        __syncthreads();
        {   // logits: 8 keys x 8 heads, 4-lane split over D
            int kr = tid >> 5, hh = (tid >> 2) & 7, part = tid & 3;
            const float* q = &qts[hh * 512 + part * 128];
            const float* e = &rows[kr * 512 + part * 128];
            float acc = 0.f;
            #pragma unroll
            for (int d = 0; d < 128; d += 4) {
                f32x4 qv = *(const f32x4*)&q[d];
                f32x4 ev = *(const f32x4*)&e[d];
                acc += qv[0] * ev[0] + qv[1] * ev[1] + qv[2] * ev[2] + qv[3] * ev[3];
            }
            acc += __shfl_xor(acc, 1);
            acc += __shfl_xor(acc, 2);
            if (part == 0) {
                float lv = (pad[b * 2048 + key0 + kr] != 0.f) ? -2e30f : acc;
                lge[hh][kr] = lv;
            }
        }
        __syncthreads();
        if (tid < 64) {  // online softmax update (wave 0)
            int hh = tid >> 3, k = tid & 7;
            float lv = lge[hh][k];
            float gm = lv;
            gm = fmaxf(gm, __shfl_xor(gm, 1));
            gm = fmaxf(gm, __shfl_xor(gm, 2));
            gm = fmaxf(gm, __shfl_xor(gm, 4));
            float mold = mh[hh];
            float mnew = fmaxf(mold, gm);
            float ev = __expf(lv - mnew);
            float gs = ev;
            gs += __shfl_xor(gs, 1); gs += __shfl_xor(gs, 2); gs += __shfl_xor(gs, 4);
            float f = __expf(mold - mnew);
            lge[hh][k] = ev;
            if (k == 0) { sh[hh] = sh[hh] * f + gs; mh[hh] = mnew; fh[hh] = f; }
        }
        __syncthreads();
        {   // z update: thread owns (h, 16 D as 4 float4s at stride 128)
            float f = fh[h];
            #pragma unroll
            for (int jj = 0; jj < 4; jj++) z4[jj] *= f;
            #pragma unroll
            for (int k = 0; k < 8; k++) {
                float ev = lge[h][k];
                #pragma unroll
                for (int jj = 0; jj < 4; jj++) {
                    f32x4 r = *(const f32x4*)&rows[k * 512 + jj * 128 + ii * 4];
                    z4[jj] += ev * r;
                }
            }
        }
        __syncthreads();
    }
    int bc = b * 16 + c;
    if (tid < 8) { Pm2[bc * 8 + tid] = mh[tid]; Ps2[bc * 8 + tid] = sh[tid]; }
    #pragma unroll
    for (int jj = 0; jj < 4; jj++)
        *(f32x4*)&Pz[((size_t)bc * 8 + h) * 512 + jj * 128 + ii * 4] = z4[jj];
}

// combine chunks + project z through Wv. grid (8 h, 4).
__global__ __launch_bounds__(256) void k_finishv_b4(
    const float* __restrict__ Pm2, const float* __restrict__ Ps2,
    const float* __restrict__ Pz,
    const float* __restrict__ Wv, const float* __restrict__ bv,
    float* __restrict__ attnb) {
    __shared__ float zs[4][512];
    int lane = threadIdx.x & 63, w = threadIdx.x >> 6;
    int h = blockIdx.x, b = blockIdx.y * 4 + w;
    float mc[16], ec[16];
    float m = -1e30f;
    #pragma unroll
    for (int cc = 0; cc < 16; cc++) { mc[cc] = Pm2[(b * 16 + cc) * 8 + h]; m = fmaxf(m, mc[cc]); }
    float S = 0.f;
    #pragma unroll
    for (int cc = 0; cc < 16; cc++) { ec[cc] = __expf(mc[cc] - m); S += ec[cc] * Ps2[(b * 16 + cc) * 8 + h]; }
    float inv = 1.f / S;
    #pragma unroll
    for (int it = 0; it < 8; it++) {
        int D = it * 64 + lane;
        float acc = 0.f;
        #pragma unroll
        for (int cc = 0; cc < 16; cc++)
            acc += ec[cc] * Pz[((size_t)(b * 16 + cc) * 8 + h) * 512 + D];
        zs[w][D] = acc * inv;
    }
    __syncthreads();
    int dv = lane;
    float acc = 0.f;
    #pragma unroll 8
    for (int D = 0; D < 512; D++) acc += zs[w][D] * Wv[(size_t)D * 512 + h * 64 + dv];
    attnb[(size_t)b * 512 + h * 64 + dv] = acc + bv[h * 64 + dv];
}

__global__ __launch_bounds__(256) void k_ffn2_b4(
    const float* __restrict__ tmp, const float* __restrict__ y2,
    const float* __restrict__ gR, const float* __restrict__ bR,
    const float* __restrict__ W2, const float* __restrict__ b2,
    float* __restrict__ y3) {
    __shared__ float ts[4][2048];
    __shared__ float xs[4][512];
    int lane = threadIdx.x & 63, w = threadIdx.x >> 6;
    int b = blockIdx.y * 4 + w;
    stage_ln_wave(y2 + (size_t)b * 512, gR, bR, 1, xs[w], lane);
    #pragma unroll
    for (int i = 0; i < 32; i++) ts[w][lane + i * 64] = tmp[(size_t)b * 2048 + lane + i * 64];
    __syncthreads();
    int col = blockIdx.x * 64 + lane;
    float acc = 0.f;
    for (int r = 0; r < 2048; r += 8) {
        #pragma unroll
        for (int j = 0; j < 8; j++) acc += ts[w][r + j] * W2[(size_t)(r + j) * 512 + col];
    }
    y3[(size_t)b * 512 + col] = acc + b2[col] + xs[w][col];
}

// ---------------------------------------------------------------------------

extern "C" void kernel_launch(void* const* d_in, const int* in_sizes, int n_in,
                              void* d_out, int out_size, void* d_ws, size_t ws_size,
                              hipStream_t stream) {
    const float* enc    = (const float*)d_in[0];
    const float* encIn  = (const float*)d_in[1];
    const float* embW   = (const float*)d_in[2];
    const float* embB   = (const float*)d_in[3];
    const float* outW   = (const float*)d_in[4];
    const float* outB   = (const float*)d_in[5];
    const float* selfW  = (const float*)d_in[6];
    const float* selfB  = (const float*)d_in[7];
    const float* crossW = (const float*)d_in[8];
    const float* crossB = (const float*)d_in[9];
    const float* fW1    = (const float*)d_in[10];
    const float* fb1    = (const float*)d_in[11];
    const float* fW2    = (const float*)d_in[12];
    const float* fb2    = (const float*)d_in[13];
    const float* lng    = (const float*)d_in[14];
    const float* lnbp   = (const float*)d_in[15];
    float* out = (float*)d_out;

    char* ws = (char*)d_ws;
    size_t off = 0;
    auto alloc = [&](size_t bytes) -> char* {
        char* p = ws + off;
        off = (off + bytes + 255) & ~(size_t)255;
        return p;
    };
    float* pad   = (float*)alloc(16 * 2048 * 4);
    float* pos   = (float*)alloc(16 * 512 * 4);
    float* x0    = (float*)alloc(16 * 512 * 4);
    float* qbuf  = (float*)alloc(16 * 512 * 4);
    float* qc    = (float*)alloc(16 * 512 * 4);
    float* y1    = (float*)alloc(16 * 512 * 4);
    float* y2    = (float*)alloc(16 * 512 * 4);
    float* y3    = (float*)alloc(16 * 512 * 4);
    float* attnb = (float*)alloc(16 * 512 * 4);
    float* qt    = (float*)alloc(16 * 8 * 512 * 4);
    float* Pm2   = (float*)alloc(16 * 16 * 8 * 4);
    float* Ps2   = (float*)alloc(16 * 16 * 8 * 4);
    float* Pz    = (float*)alloc((size_t)16 * 16 * 8 * 512 * 4);
    float* tmpb  = (float*)alloc((size_t)16 * 2048 * 4);
    float* selfKc = (float*)alloc((size_t)4 * 16 * 16 * 512 * 4);
    float* selfVc = (float*)alloc((size_t)4 * 16 * 16 * 512 * 4);
    size_t small_need = off;
    ushort_t* encbf = nullptr;
    if (off + (size_t)16 * 2048 * 512 * 2 + 512 <= ws_size)
        encbf = (ushort_t*)alloc((size_t)16 * 2048 * 512 * 2);
    if (small_need > ws_size) return;  // ws absurdly small -> zero output (diagnostic)

    // one-time setup (per launch)
    k_posenc<<<dim3(16), dim3(512), 0, stream>>>(pos);
    k_padflag<<<dim3(512, 16), dim3(256), 0, stream>>>(encIn, pad);
    if (encbf)
        k_cvt_enc<<<dim3(16384), dim3(256), 0, stream>>>(enc, encbf);

    for (int t = 0; t < 16; t++) {
        k_embed_b4<<<dim3(8, 4), dim3(256), 0, stream>>>(out, embW, embB, pos, x0, t);
        for (int l = 0; l < 4; l++) {
            const float* srcPrev = (l == 0) ? x0 : y3;
            const float* gP = (l == 0) ? nullptr : lng + ((l - 1) * 3 + 2) * 512;
            const float* bP = (l == 0) ? nullptr : lnbp + ((l - 1) * 3 + 2) * 512;
            int ulnP = (l == 0) ? 0 : 1;
            k_qkvcol<<<dim3(24, 4), dim3(256), 0, stream>>>(
                srcPrev, gP, bP, ulnP,
                selfW + (size_t)l * 4 * 262144, selfB + l * 4 * 512,
                qbuf, selfKc, selfVc, l, t);
            k_selfout_b4<<<dim3(8, 4), dim3(256), 0, stream>>>(
                srcPrev, gP, bP, ulnP, qbuf, selfKc, selfVc,
                selfW + ((size_t)l * 4 + 3) * 262144, selfB + (l * 4 + 3) * 512,
                y1, l, t);
            // qc = LN(y1)@Wq_c + bq_c
            k_colgemm_b4<<<dim3(8, 4), dim3(256), 0, stream>>>(
                y1, 1, lng + (l * 3 + 0) * 512, lnbp + (l * 3 + 0) * 512,
                nullptr, nullptr, nullptr, 0,
                crossW + (size_t)l * 4 * 262144, crossB + l * 4 * 512, 512,
                qc, 512, 0);
            k_qt_b4<<<dim3(8, 4), dim3(256), 0, stream>>>(
                qc, crossW + ((size_t)l * 4 + 1) * 262144, qt);
            if (encbf)
                k_flash2<1><<<dim3(16, 16), dim3(256), 0, stream>>>(
                    encbf, qt, pad, Pm2, Ps2, Pz);
            else
                k_flash2<0><<<dim3(16, 16), dim3(256), 0, stream>>>(
                    enc, qt, pad, Pm2, Ps2, Pz);
            k_finishv_b4<<<dim3(8, 4), dim3(256), 0, stream>>>(
                Pm2, Ps2, Pz,
                crossW + ((size_t)l * 4 + 2) * 262144, crossB + (l * 4 + 2) * 512,
                attnb);
            // y2 = attnb@Wo_c + bo_c + LN(y1)
            k_colgemm_b4<<<dim3(8, 4), dim3(256), 0, stream>>>(
                attnb, 0, nullptr, nullptr,
                y1, lng + (l * 3 + 0) * 512, lnbp + (l * 3 + 0) * 512, 1,
                crossW + ((size_t)l * 4 + 3) * 262144, crossB + (l * 4 + 3) * 512, 512,
                y2, 512, 0);
            // tmpb = relu(LN(y2)@W1 + b1)
            k_colgemm_b4<<<dim3(32, 4), dim3(256), 0, stream>>>(
                y2, 1, lng + (l * 3 + 1) * 512, lnbp + (l * 3 + 1) * 512,
                nullptr, nullptr, nullptr, 0,
                fW1 + (size_t)l * 512 * 2048, fb1 + l * 2048, 2048,
                tmpb, 2048, 1);
            k_ffn2_b4<<<dim3(8, 4), dim3(256), 0, stream>>>(
                tmpb, y2, lng + (l * 3 + 1) * 512, lnbp + (l * 3 + 1) * 512,
                fW2 + (size_t)l * 2048 * 512, fb2 + l * 512, y3);
        }
        // out[:, t, :] = LN(y3)@outW + outB
        k_colgemm_b4<<<dim3(4, 4), dim3(256), 0, stream>>>(
            y3, 1, lng + (3 * 3 + 2) * 512, lnbp + (3 * 3 + 2) * 512,
            nullptr, nullptr, nullptr, 0,
            outW, outB, 256,
            out + t * 256, 16 * 256, 0);
    }
}